// Round 2
// baseline (318.424 us; speedup 1.0000x reference)
//
#include <hip/hip_runtime.h>
#include <math.h>

// f32-rounded pi / 2pi (JAX weak-type f64->f32 folding): 0x40490FDB / 0x40C90FDB
#define PI_F        3.14159274101257324e0f
#define TWOPI_F     6.28318548202514648e0f
#define INV_TWOPI_F (1.0f / TWOPI_F)          // compile-time correctly-rounded f32

// dr2 < DR2_LT  <=>  __fsqrt_rn(dr2) < 0.05f, bit-exactly (see R1 notes):
//   boundary m = 0.05f - 2^-29; m^2 lies strictly between pred(0.0025f) and
//   0.0025f, so for f32 x:  x <= m^2  <=>  x < 0.0025f.
#define DR2_LT      0.0025f

#define ROWS_PER_BLOCK 64
#define THREADS        256
#define ROW_STRIDE     49     // 48 floats + 1 pad (odd -> conflict-free reads)

// Exact replication of jnp.mod-based dphi decision in PURE f32 (proof in R1):
//  - q = truncf(dd * fl(1/2pi)); when q is the true trunc, fma single-rounds
//    the exact remainder (f32-representable) -> bit-exact vs lax.rem; the
//    m<0 += 2pi rounded add matches jnp.mod's adjust exactly.
//  - q misrounds only when dd/2pi is ~2^-21 from an integer; there dphi ~ +/-pi
//    for BOTH paths -> dr2 ~ 9.87 >> 0.0025, decision identical.
__device__ __forceinline__ int pair_close(float ei, float ej, float pi_, float pj) {
    float deta = __fsub_rn(ei, ej);
    float dd   = __fadd_rn(__fsub_rn(pi_, pj), PI_F);
    float q    = truncf(__fmul_rn(dd, INV_TWOPI_F));
    float m    = __fmaf_rn(q, -TWOPI_F, dd);
    if (m < 0.0f) m = __fadd_rn(m, TWOPI_F);
    float dphi = __fsub_rn(m, PI_F);
    float dr2  = __fadd_rn(__fmul_rn(deta, deta), __fmul_rn(dphi, dphi));
    return dr2 < DR2_LT;
}

// Component-major row layout: float u (=4f+c) of a row lives at
//   rowbuf[rl*ROW_STRIDE + 12*(u&3) + (u>>2)].
// Writers store x/y/z/w of float4 f at base+f+{0,12,24,36} (compile-time
// ds offsets, consecutive lanes stride-1 dwords -> conflict-free).
__device__ __forceinline__ float lds_at(const float* r, int u) {
    return r[12 * (u & 3) + (u >> 2)];
}

template <int OFF, int N>
__device__ __forceinline__ unsigned group_dup(const float* r) {
    float e[N], p[N];
    int   a[N];
#pragma unroll
    for (int k = 0; k < N; ++k) {
        int u = 3 * (OFF + k);
        a[k] = lds_at(r, u + 0) > 0.0f;
        e[k] = lds_at(r, u + 1);
        p[k] = lds_at(r, u + 2);
    }
    unsigned dup = 0;
#pragma unroll
    for (int j = 0; j < N - 1; ++j) {
        int d = 0;
#pragma unroll
        for (int i = j + 1; i < N; ++i) {
            int close = pair_close(e[i], e[j], p[i], p[j]);
            d |= (a[i] & a[j] & close) | ((a[i] | a[j]) ^ 1);
        }
        if (d) dup |= (1u << (OFF + j));
    }
    return dup;
}

// Block = 256 threads handling 64 rows (3 float4 per thread).
// Smaller blocks + LDS 12.75 KB + <=64 VGPR target -> 8 blocks/CU (32-wave
// cap), double the resident blocks of v2. Finer phase granularity means some
// resident block is almost always in a memory phase -> better BW overlap.
// Data is NOT register-carried across the barriers (VGPR headroom): the store
// phase re-reads rowbuf from LDS (conflict-free, LDS pipe has slack).
template <bool FULL>
__device__ __forceinline__ void block_body(
    const float4* __restrict__ in, float4* __restrict__ out, int B,
    float* rowbuf, unsigned long long* maskbuf) {
    const int t = threadIdx.x;
    const int base4  = blockIdx.x * (ROWS_PER_BLOCK * 12);   // < 12M, fits int
    const int total4 = B * 12;

#pragma unroll
    for (int i = 0; i < 3; ++i) {
        int g = base4 + t + THREADS * i;
        if (FULL || g < total4) {
            float4 v = in[g];
            int local = t + THREADS * i;
            int rl = local / 12;
            int f  = local - rl * 12;
            float* dstp = &rowbuf[rl * ROW_STRIDE + f];
            dstp[0] = v.x; dstp[12] = v.y; dstp[24] = v.z; dstp[36] = v.w;
        }
    }
    __syncthreads();

    if (t < ROWS_PER_BLOCK) {
        int row = blockIdx.x * ROWS_PER_BLOCK + t;
        unsigned dup = 0;
        if (FULL || row < B) {
            const float* r = rowbuf + t * ROW_STRIDE;
            dup  = group_dup<0, 6>(r);    // jets      (objects 0..5)
            dup |= group_dup<6, 3>(r);    // electrons (objects 6..8)
            dup |= group_dup<9, 3>(r);    // muons     (objects 9..11)
            dup |= group_dup<12, 3>(r);   // photons   (objects 12..14)
        }
        // expand object mask -> per-float mask (bit k = zero float k, k=0..44)
        unsigned long long fm = 0ull;
#pragma unroll
        for (int o = 0; o < 15; ++o)
            fm |= (unsigned long long)((dup >> o) & 1u) * (7ull << (3 * o));
        maskbuf[t] = fm;
    }
    __syncthreads();

#pragma unroll
    for (int i = 0; i < 3; ++i) {
        int g = base4 + t + THREADS * i;
        if (FULL || g < total4) {
            int local = t + THREADS * i;
            int rl = local / 12;
            int f  = local - rl * 12;
            unsigned nib = (unsigned)(maskbuf[rl] >> (4 * f)) & 0xFu;
            const float* srcp = &rowbuf[rl * ROW_STRIDE + f];
            float4 w;
            w.x = (nib & 1u) ? 0.0f : srcp[0];
            w.y = (nib & 2u) ? 0.0f : srcp[12];
            w.z = (nib & 4u) ? 0.0f : srcp[24];
            w.w = (nib & 8u) ? 0.0f : srcp[36];
            out[g] = w;
        }
    }
}

__global__ __launch_bounds__(THREADS, 8) void dup_removal_kernel(
    const float4* __restrict__ in, float4* __restrict__ out, int B) {
    __shared__ float rowbuf[ROWS_PER_BLOCK * ROW_STRIDE];   // 12.25 KB
    __shared__ unsigned long long maskbuf[ROWS_PER_BLOCK];  // 0.5 KB

    const int base4  = blockIdx.x * (ROWS_PER_BLOCK * 12);
    const int total4 = B * 12;
    if (base4 + ROWS_PER_BLOCK * 12 <= total4)
        block_body<true>(in, out, B, rowbuf, maskbuf);
    else
        block_body<false>(in, out, B, rowbuf, maskbuf);
}

extern "C" void kernel_launch(void* const* d_in, const int* in_sizes, int n_in,
                              void* d_out, int out_size, void* d_ws, size_t ws_size,
                              hipStream_t stream) {
    const float4* x = (const float4*)d_in[0];
    float4* out = (float4*)d_out;
    int B = in_sizes[0] / 48;                            // rows of (16,3)
    int grid = (B + ROWS_PER_BLOCK - 1) / ROWS_PER_BLOCK;
    dup_removal_kernel<<<grid, THREADS, 0, stream>>>(x, out, B);
}